// Round 4
// baseline (152.274 us; speedup 1.0000x reference)
//
#include <hip/hip_runtime.h>
#include <hip/hip_bf16.h>

typedef __attribute__((ext_vector_type(8))) short short8;
typedef __attribute__((ext_vector_type(4))) float f32x4;

#define N_TOT 8192
#define HALF_B 4096
#define D 128
#define RPW 16          // rows per wave (one 16-row MFMA tile, A = 16 VGPRs)
#define BROWS 64        // rows per block (4 waves)
#define CPB 512         // columns per block
#define NQ (N_TOT / CPB)   // 16 column slices
// z is pre-scaled by SCALE with SCALE^2 = 2*log2(e); then z@z^T = sim/T*log2(e)
#define SCALE 1.6986437f
#define LN2 0.69314718f

#if __has_builtin(__builtin_amdgcn_exp2f)
  #define EXP2(x) __builtin_amdgcn_exp2f(x)
#else
  #define EXP2(x) exp2f(x)
#endif

// round-to-nearest-even float -> bf16 bits
static __device__ inline unsigned short f2bf(float f) {
    unsigned int u = __builtin_bit_cast(unsigned int, f);
    u = (u + 0x7fffu + ((u >> 16) & 1u)) >> 16;
    return (unsigned short)u;
}
static __device__ inline float bf2f(unsigned int b) {
    return __builtin_bit_cast(float, b << 16);
}

// ---- Kernel 1: L2-normalize rows, scale, emit bf16 z [8192][128] ---------
__global__ __launch_bounds__(256) void nrm_k(const float* __restrict__ pi,
                                             const float* __restrict__ pj,
                                             unsigned short* __restrict__ z) {
    int row  = (int)(blockIdx.x * 4) + (int)(threadIdx.x >> 6);
    int lane = (int)threadIdx.x & 63;
    const float* src = (row < HALF_B) ? (pi + (size_t)row * D)
                                      : (pj + (size_t)(row - HALF_B) * D);
    float2 v = *reinterpret_cast<const float2*>(src + lane * 2);
    float ss = v.x * v.x + v.y * v.y;
    #pragma unroll
    for (int off = 32; off >= 1; off >>= 1) ss += __shfl_xor(ss, off);
    float inv = SCALE / fmaxf(sqrtf(ss), 1e-8f);
    unsigned int packed = ((unsigned int)f2bf(v.y * inv) << 16) | (unsigned int)f2bf(v.x * inv);
    *reinterpret_cast<unsigned int*>(z + (size_t)row * D + lane * 2) = packed;
}

// ---- Kernel 2: z@z^T -> exp2 -> row partial sums -------------------------
// grid (N_TOT/BROWS, NQ), block 256 (4 waves x 16 rows, shared B stream).
// Small per-wave state (~55 VGPR) -> 8 waves/SIMD, no spill risk.
__global__ __launch_bounds__(256) void sim_k(const unsigned short* __restrict__ z,
                                             float* __restrict__ s_part) {
    int lane = (int)threadIdx.x & 63;
    int wid  = (int)threadIdx.x >> 6;
    int r0   = (int)blockIdx.x * BROWS + wid * RPW;
    int cq   = (int)blockIdx.y;
    int c0   = cq * CPB;
    int lr   = lane & 15;     // A-row / B-col within 16-tile
    int kg   = lane >> 4;     // k-group
    size_t laneoff = (size_t)lr * D + (size_t)kg * 8;

    // A fragments: 16 rows x K=128 in registers (16 VGPRs), loop-invariant
    short8 a[4];
    #pragma unroll
    for (int kt = 0; kt < 4; ++kt)
        a[kt] = *reinterpret_cast<const short8*>(
            z + (size_t)r0 * D + laneoff + (size_t)kt * 32);

    float s[4] = {0.0f, 0.0f, 0.0f, 0.0f};

    for (int j0 = c0; j0 < c0 + CPB; j0 += 16) {
        short8 b[4];
        const unsigned short* bp = z + (size_t)j0 * D + laneoff;
        #pragma unroll
        for (int kt = 0; kt < 4; ++kt)
            b[kt] = *reinterpret_cast<const short8*>(bp + (size_t)kt * 32);
        f32x4 acc = {0.0f, 0.0f, 0.0f, 0.0f};
        #pragma unroll
        for (int kt = 0; kt < 4; ++kt)
            acc = __builtin_amdgcn_mfma_f32_16x16x32_bf16(a[kt], b[kt], acc, 0, 0, 0);
        #pragma unroll
        for (int r = 0; r < 4; ++r)
            s[r] += EXP2(acc[r]);   // includes diag; corrected in red1_k
    }

    // reduce across the 16 columns held by each 16-lane group
    #pragma unroll
    for (int off = 1; off <= 8; off <<= 1)
        #pragma unroll
        for (int r = 0; r < 4; ++r)
            s[r] += __shfl_xor(s[r], off);

    if (lr == 0) {
        int rowbase = r0 + kg * 4;   // C/D layout: row = kg*4 + r
        #pragma unroll
        for (int r = 0; r < 4; ++r)
            s_part[(size_t)(rowbase + r) * NQ + cq] = s[r];
    }
}

// ---- Kernel 3: per-row finish, one wave per row --------------------------
// S from 16 coalesced slice reads; diag & pos via 128-d dots split over lanes
__global__ __launch_bounds__(256) void red1_k(const unsigned short* __restrict__ z,
                                              const float* __restrict__ s_part,
                                              float* __restrict__ partial) {
    int wid  = (int)threadIdx.x >> 6;
    int lane = (int)threadIdx.x & 63;
    int row  = (int)blockIdx.x * 4 + wid;

    float S = (lane < NQ) ? s_part[(size_t)row * NQ + lane] : 0.0f;

    unsigned int ua = *reinterpret_cast<const unsigned int*>(z + (size_t)row * D + lane * 2);
    unsigned int ub = *reinterpret_cast<const unsigned int*>(z + (size_t)(row ^ HALF_B) * D + lane * 2);
    float a0 = bf2f(ua & 0xffffu), a1 = bf2f(ua >> 16);
    float b0 = bf2f(ub & 0xffffu), b1 = bf2f(ub >> 16);
    float dacc = a0 * a0 + a1 * a1;
    float pacc = a0 * b0 + a1 * b1;

    #pragma unroll
    for (int off = 32; off >= 1; off >>= 1) {
        S    += __shfl_xor(S, off);
        dacc += __shfl_xor(dacc, off);
        pacc += __shfl_xor(pacc, off);
    }
    // L_i = ln(S - exp2(diag)) - pos_dot * ln2
    float Li = __logf(S - EXP2(dacc)) - pacc * LN2;

    __shared__ float ls[4];
    if (lane == 0) ls[wid] = Li;
    __syncthreads();
    if (threadIdx.x == 0)
        partial[blockIdx.x] = ls[0] + ls[1] + ls[2] + ls[3];
}

// ---- Kernel 4: final deterministic sum over 2048 partials ----------------
__global__ __launch_bounds__(1024) void red2_k(const float* __restrict__ partial,
                                               float* __restrict__ out) {
    int tid = (int)threadIdx.x;
    float v = partial[tid] + partial[tid + 1024];
    #pragma unroll
    for (int off = 32; off >= 1; off >>= 1) v += __shfl_xor(v, off);
    __shared__ float ls[16];
    if ((tid & 63) == 0) ls[tid >> 6] = v;
    __syncthreads();
    if (tid < 16) {
        float w = ls[tid];
        #pragma unroll
        for (int off = 8; off >= 1; off >>= 1) w += __shfl_xor(w, off);
        if (tid == 0) out[0] = w * (1.0f / (float)N_TOT);
    }
}

extern "C" void kernel_launch(void* const* d_in, const int* in_sizes, int n_in,
                              void* d_out, int out_size, void* d_ws, size_t ws_size,
                              hipStream_t stream) {
    const float* pi = (const float*)d_in[0];
    const float* pj = (const float*)d_in[1];
    float* out = (float*)d_out;

    unsigned short* z = (unsigned short*)d_ws;                       // 2 MiB
    float* s_part = (float*)((char*)d_ws + (size_t)N_TOT * D * 2);   // 512 KiB ([row][NQ])
    float* partial = s_part + (size_t)N_TOT * NQ;                    // 8 KiB

    nrm_k<<<dim3(N_TOT / 4), dim3(256), 0, stream>>>(pi, pj, z);
    sim_k<<<dim3(N_TOT / BROWS, NQ), dim3(256), 0, stream>>>(z, s_part);
    red1_k<<<dim3(N_TOT / 4), dim3(256), 0, stream>>>(z, s_part, partial);
    red2_k<<<dim3(1), dim3(1024), 0, stream>>>(partial, out);
}

// Round 5
// 33.132 us; speedup vs baseline: 4.5959x; 4.5959x over previous
//
#include <hip/hip_runtime.h>
#include <hip/hip_bf16.h>

typedef __attribute__((ext_vector_type(8))) short short8;
typedef __attribute__((ext_vector_type(4))) float f32x4;

#define N_TOT 8192
#define HALF_B 4096
#define D 128
#define BM 128               // rows per block
#define BN 128               // cols per B-tile step
#define NQ 8                 // column slices (grid.y)
#define SLICE (N_TOT / NQ)   // 1024 cols per block
#define NSTEP (SLICE / BN)   // 8 steps
// z pre-scaled by SCALE, SCALE^2 = 2*log2(e): z@z^T = sim/T * log2(e)
#define SCALE 1.6986437f
#define LN2 0.69314718f

#if __has_builtin(__builtin_amdgcn_exp2f)
  #define EXP2(x) __builtin_amdgcn_exp2f(x)
#else
  #define EXP2(x) exp2f(x)
#endif

static __device__ inline unsigned short f2bf(float f) {
    unsigned int u = __builtin_bit_cast(unsigned int, f);
    u = (u + 0x7fffu + ((u >> 16) & 1u)) >> 16;
    return (unsigned short)u;
}
static __device__ inline float bf2f(unsigned int b) {
    return __builtin_bit_cast(float, b << 16);
}

// async global->LDS, 16B per lane, LDS dest = wave-uniform base + lane*16
static __device__ __forceinline__ void gload16(const void* g, void* l) {
    __builtin_amdgcn_global_load_lds(
        (const __attribute__((address_space(1))) unsigned int*)g,
        (__attribute__((address_space(3))) unsigned int*)l, 16, 0, 0);
}

// Stage a 128x128 bf16 tile (z rows [src_row, src_row+128)) into 32 KB LDS,
// XOR-swizzled: LDS[r][c2 ^ ((r&7)<<4)] = z[src_row+r][c2]  (c2 = byte-in-row).
// gload_lds writes LDS linearly, so the swizzle is applied to the GLOBAL src.
static __device__ __forceinline__ void stage_tile(const unsigned short* __restrict__ z,
                                                  int src_row, char* ldsbase, int tid) {
    int wv = tid >> 6, ln = tid & 63;
    const char* zb = (const char*)z;
    #pragma unroll
    for (int i = 0; i < 8; ++i) {
        int L  = wv * 8192 + i * 1024;        // wave-uniform LDS byte offset
        int Ll = L + ln * 16;                 // this lane's dest byte
        int r  = Ll >> 8;
        int c2 = (Ll & 255) ^ ((r & 7) << 4);
        gload16(zb + (size_t)(src_row + r) * 256 + c2, ldsbase + L);
    }
}

// swizzled LDS fragment read (16B), kbyte = kg*16 + kt*64
static __device__ __forceinline__ short8 ldsfrag(const char* ldsbase, int row, int kbyte) {
    int off = row * 256 + (kbyte ^ ((row & 7) << 4));
    return *reinterpret_cast<const short8*>(ldsbase + off);
}

// ---- Kernel 1: L2-normalize rows, scale, emit bf16 z [8192][128] ---------
__global__ __launch_bounds__(256) void nrm_k(const float* __restrict__ pi,
                                             const float* __restrict__ pj,
                                             unsigned short* __restrict__ z) {
    int row  = (int)(blockIdx.x * 4) + (int)(threadIdx.x >> 6);
    int lane = (int)threadIdx.x & 63;
    const float* src = (row < HALF_B) ? (pi + (size_t)row * D)
                                      : (pj + (size_t)(row - HALF_B) * D);
    float2 v = *reinterpret_cast<const float2*>(src + lane * 2);
    float ss = v.x * v.x + v.y * v.y;
    #pragma unroll
    for (int off = 32; off >= 1; off >>= 1) ss += __shfl_xor(ss, off);
    float inv = SCALE / fmaxf(sqrtf(ss), 1e-8f);
    unsigned int packed = ((unsigned int)f2bf(v.y * inv) << 16) | (unsigned int)f2bf(v.x * inv);
    *reinterpret_cast<unsigned int*>(z + (size_t)row * D + lane * 2) = packed;
}

// ---- Kernel 2: LDS-staged z@z^T -> exp2 -> row partial sums --------------
// grid (64, NQ), block 256 (4 waves x 32 rows). m97-style 2-barrier loop.
__global__ __launch_bounds__(256, 2) void sim_k(const unsigned short* __restrict__ z,
                                                float* __restrict__ s_part) {
    __shared__ char lds[64 * 1024];
    char* Asm = lds;
    char* Bsm = lds + 32768;

    int tid  = (int)threadIdx.x;
    int lane = tid & 63;
    int wid  = tid >> 6;
    int lr   = lane & 15;     // A-row / B-col within 16-tile
    int kg   = lane >> 4;     // k-group
    int R0   = (int)blockIdx.x * BM;
    int C0   = (int)blockIdx.y * SLICE;

    stage_tile(z, R0, Asm, tid);
    stage_tile(z, C0, Bsm, tid);
    __syncthreads();

    // A fragments: wave's 32 rows x K=128, read once from LDS (32 VGPRs)
    short8 a[2][4];
    #pragma unroll
    for (int m = 0; m < 2; ++m)
        #pragma unroll
        for (int kt = 0; kt < 4; ++kt)
            a[m][kt] = ldsfrag(Asm, wid * 32 + m * 16 + lr, kg * 16 + kt * 64);

    float s[2][4];
    #pragma unroll
    for (int m = 0; m < 2; ++m)
        #pragma unroll
        for (int r = 0; r < 4; ++r) s[m][r] = 0.0f;

    for (int bs = 0; bs < NSTEP; ++bs) {
        if (bs) {
            __syncthreads();                       // readers done with Bsm
            stage_tile(z, C0 + bs * BN, Bsm, tid);
            __syncthreads();                       // stage visible (vmcnt drained)
        }
        #pragma unroll
        for (int nt = 0; nt < 8; ++nt) {
            short8 b[4];
            #pragma unroll
            for (int kt = 0; kt < 4; ++kt)
                b[kt] = ldsfrag(Bsm, nt * 16 + lr, kg * 16 + kt * 64);
            #pragma unroll
            for (int m = 0; m < 2; ++m) {
                f32x4 acc = {0.0f, 0.0f, 0.0f, 0.0f};
                #pragma unroll
                for (int kt = 0; kt < 4; ++kt)
                    acc = __builtin_amdgcn_mfma_f32_16x16x32_bf16(a[m][kt], b[kt], acc, 0, 0, 0);
                #pragma unroll
                for (int r = 0; r < 4; ++r)
                    s[m][r] += EXP2(acc[r]);   // includes diag; fixed in red1_k
            }
        }
    }

    // reduce across the 16 columns held by each 16-lane group
    #pragma unroll
    for (int off = 1; off <= 8; off <<= 1)
        #pragma unroll
        for (int m = 0; m < 2; ++m)
            #pragma unroll
            for (int r = 0; r < 4; ++r)
                s[m][r] += __shfl_xor(s[m][r], off);

    if (lr == 0) {
        int rowbase = R0 + wid * 32;
        #pragma unroll
        for (int m = 0; m < 2; ++m)
            #pragma unroll
            for (int r = 0; r < 4; ++r)
                s_part[(size_t)(rowbase + m * 16 + kg * 4 + r) * NQ + blockIdx.y] = s[m][r];
    }
}

// ---- Kernel 3: per-row finish, one wave per row --------------------------
__global__ __launch_bounds__(256) void red1_k(const unsigned short* __restrict__ z,
                                              const float* __restrict__ s_part,
                                              float* __restrict__ partial) {
    int wid  = (int)threadIdx.x >> 6;
    int lane = (int)threadIdx.x & 63;
    int row  = (int)blockIdx.x * 4 + wid;

    float S = (lane < NQ) ? s_part[(size_t)row * NQ + lane] : 0.0f;

    unsigned int ua = *reinterpret_cast<const unsigned int*>(z + (size_t)row * D + lane * 2);
    unsigned int ub = *reinterpret_cast<const unsigned int*>(z + (size_t)(row ^ HALF_B) * D + lane * 2);
    float a0 = bf2f(ua & 0xffffu), a1 = bf2f(ua >> 16);
    float b0 = bf2f(ub & 0xffffu), b1 = bf2f(ub >> 16);
    float dacc = a0 * a0 + a1 * a1;
    float pacc = a0 * b0 + a1 * b1;

    #pragma unroll
    for (int off = 32; off >= 1; off >>= 1) {
        S    += __shfl_xor(S, off);
        dacc += __shfl_xor(dacc, off);
        pacc += __shfl_xor(pacc, off);
    }
    float Li = __logf(S - EXP2(dacc)) - pacc * LN2;

    __shared__ float ls[4];
    if (lane == 0) ls[wid] = Li;
    __syncthreads();
    if (threadIdx.x == 0)
        partial[blockIdx.x] = ls[0] + ls[1] + ls[2] + ls[3];
}

// ---- Kernel 4: final deterministic sum over 2048 partials ----------------
__global__ __launch_bounds__(1024) void red2_k(const float* __restrict__ partial,
                                               float* __restrict__ out) {
    int tid = (int)threadIdx.x;
    float v = partial[tid] + partial[tid + 1024];
    #pragma unroll
    for (int off = 32; off >= 1; off >>= 1) v += __shfl_xor(v, off);
    __shared__ float ls[16];
    if ((tid & 63) == 0) ls[tid >> 6] = v;
    __syncthreads();
    if (tid < 16) {
        float w = ls[tid];
        #pragma unroll
        for (int off = 8; off >= 1; off >>= 1) w += __shfl_xor(w, off);
        if (tid == 0) out[0] = w * (1.0f / (float)N_TOT);
    }
}

extern "C" void kernel_launch(void* const* d_in, const int* in_sizes, int n_in,
                              void* d_out, int out_size, void* d_ws, size_t ws_size,
                              hipStream_t stream) {
    const float* pi = (const float*)d_in[0];
    const float* pj = (const float*)d_in[1];
    float* out = (float*)d_out;

    unsigned short* z = (unsigned short*)d_ws;                       // 2 MiB
    float* s_part = (float*)((char*)d_ws + (size_t)N_TOT * D * 2);   // 256 KiB ([row][NQ])
    float* partial = s_part + (size_t)N_TOT * NQ;                    // 8 KiB

    nrm_k<<<dim3(N_TOT / 4), dim3(256), 0, stream>>>(pi, pj, z);
    sim_k<<<dim3(N_TOT / BM, NQ), dim3(256), 0, stream>>>(z, s_part);
    red1_k<<<dim3(N_TOT / 4), dim3(256), 0, stream>>>(z, s_part, partial);
    red2_k<<<dim3(1), dim3(1024), 0, stream>>>(partial, out);
}